// Round 1
// baseline (612.558 us; speedup 1.0000x reference)
//
#include <hip/hip_runtime.h>

typedef short bf16x8 __attribute__((ext_vector_type(8)));
typedef float f32x4 __attribute__((ext_vector_type(4)));
typedef unsigned short u16;

__device__ __forceinline__ u16 f2bf(float f) {
  union { float f; unsigned u; } v; v.f = f;
  unsigned r = v.u + 0x7fffu + ((v.u >> 16) & 1u);
  return (u16)(r >> 16);
}
__device__ __forceinline__ float bf2f(u16 s) {
  union { unsigned u; float f; } v; v.u = ((unsigned)s) << 16;
  return v.f;
}

// ---------------- prep: fold nc_mixing + gauge (+1/sqrt(dk) into Q) into Wq/Wk ----------------
// WqE[j=h*64+k'][d] = scale_h * sum_e Wq[h*64+e][d] * nc[h][e][k']   (N x K layout for MFMA B-operand)
__global__ __launch_bounds__(256) void fold_kernel(
    const float* __restrict__ Wq, const float* __restrict__ Wk,
    const float* __restrict__ phase, const float* __restrict__ amp,
    const float* __restrict__ nc,
    u16* __restrict__ WqE, u16* __restrict__ WkE) {
  __shared__ float ncS[64 * 64];
  __shared__ float WS[64 * 65];
  int bid = blockIdx.x;
  int sel = bid >> 8, h = (bid >> 4) & 15, d0 = (bid & 15) * 64;
  const float* W = sel ? Wk : Wq;
  u16* O = sel ? WkE : WqE;
  float g = amp[h] * cosf(phase[h]);
  float sc = g * (sel ? 1.0f : 0.125f);  // 1/sqrt(64) folded into Q side only
  int t = threadIdx.x;
  for (int l = t; l < 4096; l += 256) ncS[l] = nc[h * 4096 + l];
  for (int l = t; l < 4096; l += 256) {
    int e = l >> 6, dd = l & 63;
    WS[e * 65 + dd] = W[(h * 64 + e) * 1024 + d0 + dd];
  }
  __syncthreads();
  int kp = t >> 2, q = t & 3;
  for (int dd = q * 16; dd < q * 16 + 16; ++dd) {
    float acc = 0.f;
#pragma unroll
    for (int e = 0; e < 64; ++e) acc += WS[e * 65 + dd] * ncS[e * 64 + kp];
    O[(h * 64 + kp) * 1024 + d0 + dd] = f2bf(acc * sc);
  }
}

__global__ __launch_bounds__(256) void cast_kernel(const float* __restrict__ src,
                                                   u16* __restrict__ dst, int n4) {
  int i = blockIdx.x * 256 + threadIdx.x;
  if (i >= n4) return;
  float4 v = ((const float4*)src)[i];
  ushort4 o;
  o.x = f2bf(v.x); o.y = f2bf(v.y); o.z = f2bf(v.z); o.w = f2bf(v.w);
  ((ushort4*)dst)[i] = o;
}

__global__ __launch_bounds__(256) void split_kernel(const float* __restrict__ src,
                                                    u16* __restrict__ hi, u16* __restrict__ lo, int n4) {
  int i = blockIdx.x * 256 + threadIdx.x;
  if (i >= n4) return;
  float4 v = ((const float4*)src)[i];
  ushort4 h, l;
  h.x = f2bf(v.x); l.x = f2bf(v.x - bf2f(h.x));
  h.y = f2bf(v.y); l.y = f2bf(v.y - bf2f(h.y));
  h.z = f2bf(v.z); l.z = f2bf(v.z - bf2f(h.z));
  h.w = f2bf(v.w); l.w = f2bf(v.w - bf2f(h.w));
  ((ushort4*)hi)[i] = h;
  ((ushort4*)lo)[i] = l;
}

// ---------------- projections: C[4096x1024] = x_bf @ W^T  (W given N x K) ----------------
// z=0 -> Qnc [bh][s][64], z=1 -> Knc [bh][s][64], z=2 -> Vt [bh][64][s] (transposed for PV)
#define LDA 72
__global__ __launch_bounds__(256) void proj_gemm(
    const u16* __restrict__ A, const u16* __restrict__ W0, const u16* __restrict__ W1,
    const u16* __restrict__ W2, u16* __restrict__ Qnc, u16* __restrict__ Knc,
    u16* __restrict__ Vt) {
  __shared__ u16 As[128 * LDA];
  __shared__ u16 Bs[128 * LDA];
  int z = blockIdx.z;
  const u16* Wp = (z == 0) ? W0 : ((z == 1) ? W1 : W2);
  int m0 = blockIdx.x * 128, n0 = blockIdx.y * 128;
  int t = threadIdx.x, lane = t & 63, wid = t >> 6;
  int wr = wid >> 1, wc = wid & 1;
  f32x4 acc[4][4] = {};
  for (int k0 = 0; k0 < 1024; k0 += 64) {
    __syncthreads();
#pragma unroll
    for (int it = 0; it < 4; ++it) {
      int q = it * 256 + t;
      int row = q >> 3, c8 = (q & 7) * 8;
      *(bf16x8*)&As[row * LDA + c8] = *(const bf16x8*)&A[(m0 + row) * 1024 + k0 + c8];
      *(bf16x8*)&Bs[row * LDA + c8] = *(const bf16x8*)&Wp[(n0 + row) * 1024 + k0 + c8];
    }
    __syncthreads();
    bf16x8 af[4][2], bfr[4][2];
#pragma unroll
    for (int m = 0; m < 4; ++m)
#pragma unroll
      for (int kk = 0; kk < 2; ++kk) {
        af[m][kk] = *(const bf16x8*)&As[(wr * 64 + m * 16 + (lane & 15)) * LDA + kk * 32 + (lane >> 4) * 8];
        bfr[m][kk] = *(const bf16x8*)&Bs[(wc * 64 + m * 16 + (lane & 15)) * LDA + kk * 32 + (lane >> 4) * 8];
      }
#pragma unroll
    for (int kk = 0; kk < 2; ++kk)
#pragma unroll
      for (int m = 0; m < 4; ++m)
#pragma unroll
        for (int n = 0; n < 4; ++n)
          acc[m][n] = __builtin_amdgcn_mfma_f32_16x16x32_bf16(af[m][kk], bfr[n][kk], acc[m][n], 0, 0, 0);
  }
#pragma unroll
  for (int m = 0; m < 4; ++m)
#pragma unroll
    for (int n = 0; n < 4; ++n)
#pragma unroll
      for (int rr = 0; rr < 4; ++rr) {
        int row = m0 + wr * 64 + m * 16 + (lane >> 4) * 4 + rr;
        int col = n0 + wc * 64 + n * 16 + (lane & 15);
        u16 v = f2bf(acc[m][n][rr]);
        int bh = (row >> 11) * 16 + (col >> 6);
        if (z == 2)
          Vt[bh * 131072 + (col & 63) * 2048 + (row & 2047)] = v;
        else if (z == 0)
          Qnc[bh * 131072 + (row & 2047) * 64 + (col & 63)] = v;
        else
          Knc[bh * 131072 + (row & 2047) * 64 + (col & 63)] = v;
      }
}

// ---------------- fused attention: scores -> softmax -> attn write -> PV ----------------
// one workgroup = (b,h, 16 query rows); scores tile 16x2048 fp32 in LDS (XOR-swizzled)
__global__ __launch_bounds__(256) void attn_kernel(
    const u16* __restrict__ Qnc, const u16* __restrict__ Knc, const u16* __restrict__ Vt,
    u16* __restrict__ ctxh, u16* __restrict__ ctxl, float* __restrict__ attn_out) {
  __shared__ float sS[16 * 2048];
  __shared__ float rinvS[16];
  int bh = blockIdx.y, i0 = blockIdx.x * 16;
  int t = threadIdx.x, lane = t & 63, wid = t >> 6;
  const u16* Qp = Qnc + bh * 131072;
  const u16* Kp = Knc + bh * 131072;
  const u16* Vp = Vt + bh * 131072;
  // Q fragments (rows i0..i0+15, K=64): already scaled by g/sqrt(dk)
  bf16x8 qa0 = *(const bf16x8*)&Qp[(i0 + (lane & 15)) * 64 + (lane >> 4) * 8];
  bf16x8 qa1 = *(const bf16x8*)&Qp[(i0 + (lane & 15)) * 64 + 32 + (lane >> 4) * 8];
  // scores: each wave covers 512 columns (32 tiles of 16)
  for (int ct = 0; ct < 32; ++ct) {
    int j0 = (wid * 32 + ct) * 16;
    bf16x8 kf0 = *(const bf16x8*)&Kp[(j0 + (lane & 15)) * 64 + (lane >> 4) * 8];
    bf16x8 kf1 = *(const bf16x8*)&Kp[(j0 + (lane & 15)) * 64 + 32 + (lane >> 4) * 8];
    f32x4 acc = {0.f, 0.f, 0.f, 0.f};
    acc = __builtin_amdgcn_mfma_f32_16x16x32_bf16(qa0, kf0, acc, 0, 0, 0);
    acc = __builtin_amdgcn_mfma_f32_16x16x32_bf16(qa1, kf1, acc, 0, 0, 0);
#pragma unroll
    for (int rr = 0; rr < 4; ++rr) {
      int row = (lane >> 4) * 4 + rr;
      int col = j0 + (lane & 15);
      sS[row * 2048 + (col ^ ((row & 7) << 2))] = acc[rr];
    }
  }
  __syncthreads();
  // softmax: 16 threads per row, fp32
  {
    int row = t >> 4, sub = t & 15;
    int sw = (row & 7) << 2;
    float m = -1e30f;
    for (int n = 0; n < 32; ++n) {
      int c = (sub + n * 16) * 4;
      f32x4 v = *(const f32x4*)&sS[row * 2048 + (c ^ sw)];
      m = fmaxf(fmaxf(fmaxf(m, v[0]), fmaxf(v[1], v[2])), v[3]);
    }
#pragma unroll
    for (int off = 1; off < 16; off <<= 1) m = fmaxf(m, __shfl_xor(m, off));
    float sum = 0.f;
    for (int n = 0; n < 32; ++n) {
      int c = (sub + n * 16) * 4;
      f32x4 v = *(const f32x4*)&sS[row * 2048 + (c ^ sw)];
      f32x4 e;
      e[0] = __expf(v[0] - m); e[1] = __expf(v[1] - m);
      e[2] = __expf(v[2] - m); e[3] = __expf(v[3] - m);
      *(f32x4*)&sS[row * 2048 + (c ^ sw)] = e;
      sum += (e[0] + e[1]) + (e[2] + e[3]);
    }
#pragma unroll
    for (int off = 1; off < 16; off <<= 1) sum += __shfl_xor(sum, off);
    if (sub == 0) rinvS[row] = 1.0f / sum;
  }
  __syncthreads();
  // attn write (coalesced float4)
  {
    float* ao = attn_out + (size_t)bh * 2048 * 2048 + (size_t)i0 * 2048;
    for (int it = 0; it < 32; ++it) {
      int l = it * 256 + t;
      int r = l >> 9, g4 = (l & 511) * 4;
      int swr = (r & 7) << 2;
      f32x4 v = *(const f32x4*)&sS[r * 2048 + (g4 ^ swr)];
      float ri = rinvS[r];
      f32x4 o = {v[0] * ri, v[1] * ri, v[2] * ri, v[3] * ri};
      *(f32x4*)&ao[r * 2048 + g4] = o;
    }
  }
  // PV: ctx[16 x 64], each wave owns 16 d'-columns; accumulate unnormalized, rescale at end
  f32x4 acc0 = {0.f, 0.f, 0.f, 0.f}, acc1 = {0.f, 0.f, 0.f, 0.f};
  {
    int arow = lane & 15;
    int asw = (arow & 7) << 2;
    const float* aBase = &sS[arow * 2048];
    const u16* vBase = &Vp[(wid * 16 + (lane & 15)) * 2048];
    for (int s0 = 0; s0 < 2048; s0 += 64) {
#pragma unroll
      for (int half = 0; half < 2; ++half) {
        int k0 = s0 + half * 32 + (lane >> 4) * 8;
        f32x4 e0 = *(const f32x4*)&aBase[k0 ^ asw];
        f32x4 e1 = *(const f32x4*)&aBase[(k0 + 4) ^ asw];
        bf16x8 afr;
        afr[0] = (short)f2bf(e0[0]); afr[1] = (short)f2bf(e0[1]);
        afr[2] = (short)f2bf(e0[2]); afr[3] = (short)f2bf(e0[3]);
        afr[4] = (short)f2bf(e1[0]); afr[5] = (short)f2bf(e1[1]);
        afr[6] = (short)f2bf(e1[2]); afr[7] = (short)f2bf(e1[3]);
        bf16x8 bv = *(const bf16x8*)&vBase[k0];
        if (half == 0)
          acc0 = __builtin_amdgcn_mfma_f32_16x16x32_bf16(afr, bv, acc0, 0, 0, 0);
        else
          acc1 = __builtin_amdgcn_mfma_f32_16x16x32_bf16(afr, bv, acc1, 0, 0, 0);
      }
    }
  }
  {
    int b = bh >> 4, h = bh & 15;
#pragma unroll
    for (int rr = 0; rr < 4; ++rr) {
      int r = (lane >> 4) * 4 + rr;
      float val = (acc0[rr] + acc1[rr]) * rinvS[r];
      int idx = (b * 2048 + i0 + r) * 1024 + h * 64 + wid * 16 + (lane & 15);
      u16 hi = f2bf(val);
      ctxh[idx] = hi;
      ctxl[idx] = f2bf(val - bf2f(hi));
    }
  }
}

// ---------------- out projection: out = ctx @ Wo^T + bo, hi/lo split (3-term) ----------------
#define LDO 40
__global__ __launch_bounds__(256) void outproj_gemm(
    const u16* __restrict__ ch, const u16* __restrict__ cl,
    const u16* __restrict__ wh, const u16* __restrict__ wl,
    const float* __restrict__ bo, float* __restrict__ out) {
  __shared__ u16 Ah[128 * LDO], Al[128 * LDO], Bh[128 * LDO], Bl[128 * LDO];
  int m0 = blockIdx.x * 128, n0 = blockIdx.y * 128;
  int t = threadIdx.x, lane = t & 63, wid = t >> 6;
  int wr = wid >> 1, wc = wid & 1;
  f32x4 acc[4][4] = {};
  for (int k0 = 0; k0 < 1024; k0 += 32) {
    __syncthreads();
#pragma unroll
    for (int it = 0; it < 2; ++it) {
      int q = it * 256 + t;
      int row = q >> 2, c8 = (q & 3) * 8;
      *(bf16x8*)&Ah[row * LDO + c8] = *(const bf16x8*)&ch[(m0 + row) * 1024 + k0 + c8];
      *(bf16x8*)&Al[row * LDO + c8] = *(const bf16x8*)&cl[(m0 + row) * 1024 + k0 + c8];
      *(bf16x8*)&Bh[row * LDO + c8] = *(const bf16x8*)&wh[(n0 + row) * 1024 + k0 + c8];
      *(bf16x8*)&Bl[row * LDO + c8] = *(const bf16x8*)&wl[(n0 + row) * 1024 + k0 + c8];
    }
    __syncthreads();
    bf16x8 ah[4], al[4], bhf[4], blf[4];
#pragma unroll
    for (int m = 0; m < 4; ++m) {
      int ar = (wr * 64 + m * 16 + (lane & 15)) * LDO + (lane >> 4) * 8;
      int br = (wc * 64 + m * 16 + (lane & 15)) * LDO + (lane >> 4) * 8;
      ah[m] = *(const bf16x8*)&Ah[ar];
      al[m] = *(const bf16x8*)&Al[ar];
      bhf[m] = *(const bf16x8*)&Bh[br];
      blf[m] = *(const bf16x8*)&Bl[br];
    }
#pragma unroll
    for (int m = 0; m < 4; ++m)
#pragma unroll
      for (int n = 0; n < 4; ++n) {
        acc[m][n] = __builtin_amdgcn_mfma_f32_16x16x32_bf16(ah[m], bhf[n], acc[m][n], 0, 0, 0);
        acc[m][n] = __builtin_amdgcn_mfma_f32_16x16x32_bf16(ah[m], blf[n], acc[m][n], 0, 0, 0);
        acc[m][n] = __builtin_amdgcn_mfma_f32_16x16x32_bf16(al[m], bhf[n], acc[m][n], 0, 0, 0);
      }
  }
#pragma unroll
  for (int m = 0; m < 4; ++m)
#pragma unroll
    for (int n = 0; n < 4; ++n)
#pragma unroll
      for (int rr = 0; rr < 4; ++rr) {
        int row = m0 + wr * 64 + m * 16 + (lane >> 4) * 4 + rr;
        int col = n0 + wc * 64 + n * 16 + (lane & 15);
        out[row * 1024 + col] = acc[m][n][rr] + bo[col];
      }
}

extern "C" void kernel_launch(void* const* d_in, const int* in_sizes, int n_in,
                              void* d_out, int out_size, void* d_ws, size_t ws_size,
                              hipStream_t stream) {
  const float* x = (const float*)d_in[0];
  const float* Wq = (const float*)d_in[1];
  const float* Wk = (const float*)d_in[2];
  const float* Wv = (const float*)d_in[3];
  const float* Wo = (const float*)d_in[4];
  const float* bo = (const float*)d_in[5];
  const float* phase = (const float*)d_in[6];
  const float* amp = (const float*)d_in[7];
  const float* nc = (const float*)d_in[8];

  float* out0 = (float*)d_out;
  float* attn = out0 + 4194304;  // out (2,2048,1024) then attn (2,16,2048,2048)

  u16* x_bf = (u16*)d_ws;          // 4096x1024
  u16* Qnc = x_bf + 4194304;       // [32][2048][64]
  u16* Knc = Qnc + 4194304;
  u16* Vt = Knc + 4194304;         // [32][64][2048]
  u16* ctxh = Vt + 4194304;        // 4096x1024
  u16* ctxl = ctxh + 4194304;
  u16* WqE = ctxl + 4194304;       // 1024x1024 each
  u16* WkE = WqE + 1048576;
  u16* Wvb = WkE + 1048576;
  u16* Woh = Wvb + 1048576;
  u16* Wol = Woh + 1048576;

  fold_kernel<<<dim3(512), dim3(256), 0, stream>>>(Wq, Wk, phase, amp, nc, WqE, WkE);
  cast_kernel<<<dim3(4096), dim3(256), 0, stream>>>(x, x_bf, 1048576);
  cast_kernel<<<dim3(1024), dim3(256), 0, stream>>>(Wv, Wvb, 262144);
  split_kernel<<<dim3(1024), dim3(256), 0, stream>>>(Wo, Woh, Wol, 262144);
  proj_gemm<<<dim3(32, 8, 3), dim3(256), 0, stream>>>(x_bf, WqE, WkE, Wvb, Qnc, Knc, Vt);
  attn_kernel<<<dim3(128, 32), dim3(256), 0, stream>>>(Qnc, Knc, Vt, ctxh, ctxl, attn);
  outproj_gemm<<<dim3(32, 8), dim3(256), 0, stream>>>(ctxh, ctxl, Woh, Wol, bo, out0);
}

// Round 2
// 376.922 us; speedup vs baseline: 1.6252x; 1.6252x over previous
//
#include <hip/hip_runtime.h>

typedef short bf16x8 __attribute__((ext_vector_type(8)));
typedef float f32x4 __attribute__((ext_vector_type(4)));
typedef unsigned short u16;

__device__ __forceinline__ u16 f2bf(float f) {
  union { float f; unsigned u; } v; v.f = f;
  unsigned r = v.u + 0x7fffu + ((v.u >> 16) & 1u);
  return (u16)(r >> 16);
}
__device__ __forceinline__ float bf2f(u16 s) {
  union { unsigned u; float f; } v; v.u = ((unsigned)s) << 16;
  return v.f;
}

// ---------------- prep: fold nc_mixing + gauge (+1/sqrt(dk) into Q) into Wq/Wk ----------------
__global__ __launch_bounds__(256) void fold_kernel(
    const float* __restrict__ Wq, const float* __restrict__ Wk,
    const float* __restrict__ phase, const float* __restrict__ amp,
    const float* __restrict__ nc,
    u16* __restrict__ WqE, u16* __restrict__ WkE) {
  __shared__ float ncS[64 * 64];
  __shared__ float WS[64 * 65];
  int bid = blockIdx.x;
  int sel = bid >> 8, h = (bid >> 4) & 15, d0 = (bid & 15) * 64;
  const float* W = sel ? Wk : Wq;
  u16* O = sel ? WkE : WqE;
  float g = amp[h] * cosf(phase[h]);
  float sc = g * (sel ? 1.0f : 0.125f);  // 1/sqrt(64) folded into Q side only
  int t = threadIdx.x;
  for (int l = t; l < 4096; l += 256) ncS[l] = nc[h * 4096 + l];
  for (int l = t; l < 4096; l += 256) {
    int e = l >> 6, dd = l & 63;
    WS[e * 65 + dd] = W[(h * 64 + e) * 1024 + d0 + dd];
  }
  __syncthreads();
  int kp = t >> 2, q = t & 3;
  for (int dd = q * 16; dd < q * 16 + 16; ++dd) {
    float acc = 0.f;
#pragma unroll
    for (int e = 0; e < 64; ++e) acc += WS[e * 65 + dd] * ncS[e * 64 + kp];
    O[(h * 64 + kp) * 1024 + d0 + dd] = f2bf(acc * sc);
  }
}

__global__ __launch_bounds__(256) void cast_kernel(const float* __restrict__ src,
                                                   u16* __restrict__ dst, int n4) {
  int i = blockIdx.x * 256 + threadIdx.x;
  if (i >= n4) return;
  float4 v = ((const float4*)src)[i];
  ushort4 o;
  o.x = f2bf(v.x); o.y = f2bf(v.y); o.z = f2bf(v.z); o.w = f2bf(v.w);
  ((ushort4*)dst)[i] = o;
}

__global__ __launch_bounds__(256) void split_kernel(const float* __restrict__ src,
                                                    u16* __restrict__ hi, u16* __restrict__ lo, int n4) {
  int i = blockIdx.x * 256 + threadIdx.x;
  if (i >= n4) return;
  float4 v = ((const float4*)src)[i];
  ushort4 h, l;
  h.x = f2bf(v.x); l.x = f2bf(v.x - bf2f(h.x));
  h.y = f2bf(v.y); l.y = f2bf(v.y - bf2f(h.y));
  h.z = f2bf(v.z); l.z = f2bf(v.z - bf2f(h.z));
  h.w = f2bf(v.w); l.w = f2bf(v.w - bf2f(h.w));
  ((ushort4*)hi)[i] = h;
  ((ushort4*)lo)[i] = l;
}

// ---------------- projections: C[4096x1024] = x_bf @ W^T  (W given N x K) ----------------
#define LDA 72
__global__ __launch_bounds__(256) void proj_gemm(
    const u16* __restrict__ A, const u16* __restrict__ W0, const u16* __restrict__ W1,
    const u16* __restrict__ W2, u16* __restrict__ Qnc, u16* __restrict__ Knc,
    u16* __restrict__ Vt) {
  __shared__ u16 As[128 * LDA];
  __shared__ u16 Bs[128 * LDA];
  int z = blockIdx.z;
  const u16* Wp = (z == 0) ? W0 : ((z == 1) ? W1 : W2);
  int m0 = blockIdx.x * 128, n0 = blockIdx.y * 128;
  int t = threadIdx.x, lane = t & 63, wid = t >> 6;
  int wr = wid >> 1, wc = wid & 1;
  f32x4 acc[4][4] = {};
  for (int k0 = 0; k0 < 1024; k0 += 64) {
    __syncthreads();
#pragma unroll
    for (int it = 0; it < 4; ++it) {
      int q = it * 256 + t;
      int row = q >> 3, c8 = (q & 7) * 8;
      *(bf16x8*)&As[row * LDA + c8] = *(const bf16x8*)&A[(m0 + row) * 1024 + k0 + c8];
      *(bf16x8*)&Bs[row * LDA + c8] = *(const bf16x8*)&Wp[(n0 + row) * 1024 + k0 + c8];
    }
    __syncthreads();
    bf16x8 af[4][2], bfr[4][2];
#pragma unroll
    for (int m = 0; m < 4; ++m)
#pragma unroll
      for (int kk = 0; kk < 2; ++kk) {
        af[m][kk] = *(const bf16x8*)&As[(wr * 64 + m * 16 + (lane & 15)) * LDA + kk * 32 + (lane >> 4) * 8];
        bfr[m][kk] = *(const bf16x8*)&Bs[(wc * 64 + m * 16 + (lane & 15)) * LDA + kk * 32 + (lane >> 4) * 8];
      }
#pragma unroll
    for (int kk = 0; kk < 2; ++kk)
#pragma unroll
      for (int m = 0; m < 4; ++m)
#pragma unroll
        for (int n = 0; n < 4; ++n)
          acc[m][n] = __builtin_amdgcn_mfma_f32_16x16x32_bf16(af[m][kk], bfr[n][kk], acc[m][n], 0, 0, 0);
  }
#pragma unroll
  for (int m = 0; m < 4; ++m)
#pragma unroll
    for (int n = 0; n < 4; ++n)
#pragma unroll
      for (int rr = 0; rr < 4; ++rr) {
        int row = m0 + wr * 64 + m * 16 + (lane >> 4) * 4 + rr;
        int col = n0 + wc * 64 + n * 16 + (lane & 15);
        u16 v = f2bf(acc[m][n][rr]);
        int bh = (row >> 11) * 16 + (col >> 6);
        if (z == 2)
          Vt[bh * 131072 + (col & 63) * 2048 + (row & 2047)] = v;
        else if (z == 0)
          Qnc[bh * 131072 + (row & 2047) * 64 + (col & 63)] = v;
        else
          Knc[bh * 131072 + (row & 2047) * 64 + (col & 63)] = v;
      }
}

// ---------------- fused attention v2: barrier-free two-pass flash per wave ----------------
// block = 4 waves x 32 rows = 128 query rows per (b,h); grid (16, 32).
// pass 1: online (m,l) over all 2048 cols in registers; shfl-merge.
// pass 2: recompute scores, write normalized attn (nontemporal), PV via tiny per-wave LDS.
#define PSTR 40
__global__ __launch_bounds__(256) void attn_kernel(
    const u16* __restrict__ Qnc, const u16* __restrict__ Knc, const u16* __restrict__ Vt,
    u16* __restrict__ ctxh, u16* __restrict__ ctxl, float* __restrict__ attn_out) {
  __shared__ u16 P[4][32 * PSTR];
  int bh = blockIdx.y;
  int t = threadIdx.x, lane = t & 63, wid = t >> 6;
  int g = lane >> 4, li = lane & 15;
  int i0 = blockIdx.x * 128 + wid * 32;
  const u16* Qp = Qnc + bh * 131072;
  const u16* Kp = Knc + bh * 131072;
  const u16* Vp = Vt + bh * 131072;
  u16* Pw = &P[wid][0];

  // Q fragments: rows i0 + rb*16 + li, k-slices
  bf16x8 qf[2][2];
#pragma unroll
  for (int rb = 0; rb < 2; ++rb)
#pragma unroll
    for (int h2 = 0; h2 < 2; ++h2)
      qf[rb][h2] = *(const bf16x8*)&Qp[(i0 + rb * 16 + li) * 64 + h2 * 32 + g * 8];

  float m[2][4], l[2][4];
#pragma unroll
  for (int rb = 0; rb < 2; ++rb)
#pragma unroll
    for (int rr = 0; rr < 4; ++rr) { m[rb][rr] = -1e30f; l[rb][rr] = 0.f; }

  // ---- pass 1: online max/sum ----
  for (int s0 = 0; s0 < 2048; s0 += 32) {
    bf16x8 kf[2][2];
#pragma unroll
    for (int ct = 0; ct < 2; ++ct)
#pragma unroll
      for (int h2 = 0; h2 < 2; ++h2)
        kf[ct][h2] = *(const bf16x8*)&Kp[(s0 + ct * 16 + li) * 64 + h2 * 32 + g * 8];
    f32x4 acc[2][2] = {};
#pragma unroll
    for (int rb = 0; rb < 2; ++rb)
#pragma unroll
      for (int ct = 0; ct < 2; ++ct) {
        acc[rb][ct] = __builtin_amdgcn_mfma_f32_16x16x32_bf16(qf[rb][0], kf[ct][0], acc[rb][ct], 0, 0, 0);
        acc[rb][ct] = __builtin_amdgcn_mfma_f32_16x16x32_bf16(qf[rb][1], kf[ct][1], acc[rb][ct], 0, 0, 0);
      }
#pragma unroll
    for (int rb = 0; rb < 2; ++rb)
#pragma unroll
      for (int rr = 0; rr < 4; ++rr) {
        float a0 = acc[rb][0][rr], a1 = acc[rb][1][rr];
        float mn = fmaxf(m[rb][rr], fmaxf(a0, a1));
        l[rb][rr] = l[rb][rr] * __expf(m[rb][rr] - mn) + __expf(a0 - mn) + __expf(a1 - mn);
        m[rb][rr] = mn;
      }
  }
  // merge (m,l) across the 16 lanes sharing a row (col classes mod 16)
#pragma unroll
  for (int rb = 0; rb < 2; ++rb)
#pragma unroll
    for (int rr = 0; rr < 4; ++rr) {
      float mm = m[rb][rr], ll = l[rb][rr];
#pragma unroll
      for (int off = 1; off < 16; off <<= 1) {
        float m2 = __shfl_xor(mm, off);
        float l2 = __shfl_xor(ll, off);
        float mn = fmaxf(mm, m2);
        ll = ll * __expf(mm - mn) + l2 * __expf(m2 - mn);
        mm = mn;
      }
      m[rb][rr] = mm;
      l[rb][rr] = 1.0f / ll;  // rinv
    }

  // ---- pass 2: recompute, write attn, PV ----
  f32x4 ctx[2][4] = {};  // [rb][dt]
  float* ao = attn_out + (size_t)bh * 4194304;
  for (int s0 = 0; s0 < 2048; s0 += 32) {
    bf16x8 kf[2][2];
#pragma unroll
    for (int ct = 0; ct < 2; ++ct)
#pragma unroll
      for (int h2 = 0; h2 < 2; ++h2)
        kf[ct][h2] = *(const bf16x8*)&Kp[(s0 + ct * 16 + li) * 64 + h2 * 32 + g * 8];
    f32x4 acc[2][2] = {};
#pragma unroll
    for (int rb = 0; rb < 2; ++rb)
#pragma unroll
      for (int ct = 0; ct < 2; ++ct) {
        acc[rb][ct] = __builtin_amdgcn_mfma_f32_16x16x32_bf16(qf[rb][0], kf[ct][0], acc[rb][ct], 0, 0, 0);
        acc[rb][ct] = __builtin_amdgcn_mfma_f32_16x16x32_bf16(qf[rb][1], kf[ct][1], acc[rb][ct], 0, 0, 0);
      }
    // normalized p; stream to attn_out; stage bf16 into per-wave LDS tile
#pragma unroll
    for (int rb = 0; rb < 2; ++rb)
#pragma unroll
      for (int ct = 0; ct < 2; ++ct)
#pragma unroll
        for (int rr = 0; rr < 4; ++rr) {
          float p = __expf(acc[rb][ct][rr] - m[rb][rr]) * l[rb][rr];
          acc[rb][ct][rr] = p;
          int q = i0 + rb * 16 + g * 4 + rr;
          __builtin_nontemporal_store(p, &ao[(size_t)q * 2048 + s0 + ct * 16 + li]);
        }
#pragma unroll
    for (int rb = 0; rb < 2; ++rb)
#pragma unroll
      for (int ct = 0; ct < 2; ++ct)
#pragma unroll
        for (int rr = 0; rr < 4; ++rr) {
          int row = rb * 16 + g * 4 + rr;
          int col = (ct * 16 + li) ^ (g << 3);
          Pw[row * PSTR + col] = f2bf(acc[rb][ct][rr]);
        }
    // A-fragments from LDS (swizzled), V B-fragments from global, PV MFMAs
    bf16x8 pa[2];
    int xbq = (li >> 2) & 3;
#pragma unroll
    for (int rb = 0; rb < 2; ++rb)
      pa[rb] = *(const bf16x8*)&Pw[(rb * 16 + li) * PSTR + ((g ^ xbq) * 8)];
#pragma unroll
    for (int dt = 0; dt < 4; ++dt) {
      bf16x8 vf = *(const bf16x8*)&Vp[(dt * 16 + li) * 2048 + s0 + g * 8];
#pragma unroll
      for (int rb = 0; rb < 2; ++rb)
        ctx[rb][dt] = __builtin_amdgcn_mfma_f32_16x16x32_bf16(pa[rb], vf, ctx[rb][dt], 0, 0, 0);
    }
  }
  // epilogue: ctx hi/lo bf16
  int b = bh >> 4, hh = bh & 15;
#pragma unroll
  for (int rb = 0; rb < 2; ++rb)
#pragma unroll
    for (int dt = 0; dt < 4; ++dt)
#pragma unroll
      for (int rr = 0; rr < 4; ++rr) {
        int q = i0 + rb * 16 + g * 4 + rr;
        int idx = (b * 2048 + q) * 1024 + hh * 64 + dt * 16 + li;
        float val = ctx[rb][dt][rr];
        u16 hi = f2bf(val);
        ctxh[idx] = hi;
        ctxl[idx] = f2bf(val - bf2f(hi));
      }
}

// ---------------- out projection: out = ctx @ Wo^T + bo, hi/lo split (3-term) ----------------
#define LDO 40
__global__ __launch_bounds__(256) void outproj_gemm(
    const u16* __restrict__ ch, const u16* __restrict__ cl,
    const u16* __restrict__ wh, const u16* __restrict__ wl,
    const float* __restrict__ bo, float* __restrict__ out) {
  __shared__ u16 Ah[128 * LDO], Al[128 * LDO], Bh[128 * LDO], Bl[128 * LDO];
  int m0 = blockIdx.x * 128, n0 = blockIdx.y * 128;
  int t = threadIdx.x, lane = t & 63, wid = t >> 6;
  int wr = wid >> 1, wc = wid & 1;
  f32x4 acc[4][4] = {};
  for (int k0 = 0; k0 < 1024; k0 += 32) {
    __syncthreads();
#pragma unroll
    for (int it = 0; it < 2; ++it) {
      int q = it * 256 + t;
      int row = q >> 2, c8 = (q & 3) * 8;
      *(bf16x8*)&Ah[row * LDO + c8] = *(const bf16x8*)&ch[(m0 + row) * 1024 + k0 + c8];
      *(bf16x8*)&Al[row * LDO + c8] = *(const bf16x8*)&cl[(m0 + row) * 1024 + k0 + c8];
      *(bf16x8*)&Bh[row * LDO + c8] = *(const bf16x8*)&wh[(n0 + row) * 1024 + k0 + c8];
      *(bf16x8*)&Bl[row * LDO + c8] = *(const bf16x8*)&wl[(n0 + row) * 1024 + k0 + c8];
    }
    __syncthreads();
    bf16x8 ah[4], al[4], bhf[4], blf[4];
#pragma unroll
    for (int m = 0; m < 4; ++m) {
      int ar = (wr * 64 + m * 16 + (lane & 15)) * LDO + (lane >> 4) * 8;
      int br = (wc * 64 + m * 16 + (lane & 15)) * LDO + (lane >> 4) * 8;
      ah[m] = *(const bf16x8*)&Ah[ar];
      al[m] = *(const bf16x8*)&Al[ar];
      bhf[m] = *(const bf16x8*)&Bh[br];
      blf[m] = *(const bf16x8*)&Bl[br];
    }
#pragma unroll
    for (int m = 0; m < 4; ++m)
#pragma unroll
      for (int n = 0; n < 4; ++n) {
        acc[m][n] = __builtin_amdgcn_mfma_f32_16x16x32_bf16(ah[m], bhf[n], acc[m][n], 0, 0, 0);
        acc[m][n] = __builtin_amdgcn_mfma_f32_16x16x32_bf16(ah[m], blf[n], acc[m][n], 0, 0, 0);
        acc[m][n] = __builtin_amdgcn_mfma_f32_16x16x32_bf16(al[m], bhf[n], acc[m][n], 0, 0, 0);
      }
  }
#pragma unroll
  for (int m = 0; m < 4; ++m)
#pragma unroll
    for (int n = 0; n < 4; ++n)
#pragma unroll
      for (int rr = 0; rr < 4; ++rr) {
        int row = m0 + wr * 64 + m * 16 + (lane >> 4) * 4 + rr;
        int col = n0 + wc * 64 + n * 16 + (lane & 15);
        out[row * 1024 + col] = acc[m][n][rr] + bo[col];
      }
}

extern "C" void kernel_launch(void* const* d_in, const int* in_sizes, int n_in,
                              void* d_out, int out_size, void* d_ws, size_t ws_size,
                              hipStream_t stream) {
  const float* x = (const float*)d_in[0];
  const float* Wq = (const float*)d_in[1];
  const float* Wk = (const float*)d_in[2];
  const float* Wv = (const float*)d_in[3];
  const float* Wo = (const float*)d_in[4];
  const float* bo = (const float*)d_in[5];
  const float* phase = (const float*)d_in[6];
  const float* amp = (const float*)d_in[7];
  const float* nc = (const float*)d_in[8];

  float* out0 = (float*)d_out;
  float* attn = out0 + 4194304;  // out (2,2048,1024) then attn (2,16,2048,2048)

  u16* x_bf = (u16*)d_ws;          // 4096x1024
  u16* Qnc = x_bf + 4194304;       // [32][2048][64]
  u16* Knc = Qnc + 4194304;
  u16* Vt = Knc + 4194304;         // [32][64][2048]
  u16* ctxh = Vt + 4194304;        // 4096x1024
  u16* ctxl = ctxh + 4194304;
  u16* WqE = ctxl + 4194304;       // 1024x1024 each
  u16* WkE = WqE + 1048576;
  u16* Wvb = WkE + 1048576;
  u16* Woh = Wvb + 1048576;
  u16* Wol = Woh + 1048576;

  fold_kernel<<<dim3(512), dim3(256), 0, stream>>>(Wq, Wk, phase, amp, nc, WqE, WkE);
  cast_kernel<<<dim3(4096), dim3(256), 0, stream>>>(x, x_bf, 1048576);
  cast_kernel<<<dim3(1024), dim3(256), 0, stream>>>(Wv, Wvb, 262144);
  split_kernel<<<dim3(1024), dim3(256), 0, stream>>>(Wo, Woh, Wol, 262144);
  proj_gemm<<<dim3(32, 8, 3), dim3(256), 0, stream>>>(x_bf, WqE, WkE, Wvb, Qnc, Knc, Vt);
  attn_kernel<<<dim3(16, 32), dim3(256), 0, stream>>>(Qnc, Knc, Vt, ctxh, ctxl, attn);
  outproj_gemm<<<dim3(32, 8), dim3(256), 0, stream>>>(ctxh, ctxl, Woh, Wol, bo, out0);
}